// Round 2
// baseline (1579.446 us; speedup 1.0000x reference)
//
#include <hip/hip_runtime.h>

// Problem constants (fixed-shape problem)
#define GDIM 256
#define DDIM 20
#define HID 150
#define HID_P 152          // padded hidden (mult of 4, rows 16B-aligned)
#define NB_H4 (HID_P/4)    // 38
#define KMAX 250
#define NMAX 2000

// workspace layout (floats)
#define OFF_U   0
#define OFF_V   (OFF_U + NMAX*HID_P)
#define OFF_D   (OFF_V + NMAX*HID_P)
#define OFF_WC  (OFF_D + 9*HID_P)
#define OFF_W2  (OFF_WC + GDIM*HID_P)
#define OFF_W3  (OFF_W2 + HID_P*HID_P)
#define OFF_B2  (OFF_W3 + HID_P)

// ---------------------------------------------------------------------------
// Kernel 1a: U[i] = i_g @ W1[0:256] + b1 ;  V[j] = j_g @ W1[256:512]
// ---------------------------------------------------------------------------
__global__ void precompute_uv(const float* __restrict__ g_i,
                              const float* __restrict__ W1,
                              const float* __restrict__ b1,
                              float* __restrict__ ws, int N) {
  int t = blockIdx.x * blockDim.x + threadIdx.x;
  int total = N * HID_P;
  bool isV = false;
  if (t >= total) { t -= total; isV = true; }
  if (t >= total) return;
  int r = t / HID_P, c = t - (t / HID_P) * HID_P;
  float acc = 0.f;
  if (c < HID) {
    const float* w = W1 + (isV ? GDIM * HID : 0) + c;
    const float* g = g_i + (size_t)r * GDIM;
#pragma unroll 8
    for (int k = 0; k < GDIM; k++) acc = fmaf(g[k], w[(size_t)k * HID], acc);
    if (!isV) acc += b1[c];
  }
  ws[(isV ? OFF_V : OFF_U) + (size_t)r * HID_P + c] = acc;
}

// ---------------------------------------------------------------------------
// Kernel 1b: distance table, padded weight copies
// ---------------------------------------------------------------------------
__global__ void precompute_tabs(const float* __restrict__ dist_embed,
                                const float* __restrict__ W1,
                                const float* __restrict__ W2,
                                const float* __restrict__ b2,
                                const float* __restrict__ W3,
                                float* __restrict__ ws) {
  int t = blockIdx.x * blockDim.x + threadIdx.x;
  if (t < 9 * HID_P) {                               // D[d] = dist_embed[d] @ W1[768:788]
    int d = t / HID_P, c = t - d * HID_P;
    float a = 0.f;
    if (c < HID) {
#pragma unroll
      for (int k = 0; k < DDIM; k++)
        a = fmaf(dist_embed[d * DDIM + k], W1[(size_t)(3 * GDIM + k) * HID + c], a);
    }
    ws[OFF_D + t] = a;
    return;
  }
  t -= 9 * HID_P;
  if (t < GDIM * HID_P) {                            // Wc padded copy (rows of W1[512:768])
    int k = t / HID_P, c = t - k * HID_P;
    ws[OFF_WC + t] = (c < HID) ? W1[(size_t)(2 * GDIM + k) * HID + c] : 0.f;
    return;
  }
  t -= GDIM * HID_P;
  if (t < HID_P * HID_P) {                           // W2 padded copy
    int k = t / HID_P, c = t - k * HID_P;
    ws[OFF_W2 + t] = (k < HID && c < HID) ? W2[(size_t)k * HID + c] : 0.f;
    return;
  }
  t -= HID_P * HID_P;
  if (t < HID_P) { ws[OFF_W3 + t] = (t < HID) ? W3[t] : 0.f; return; }
  t -= HID_P;
  if (t < HID_P) { ws[OFF_B2 + t] = (t < HID) ? b2[t] : 0.f; return; }
}

// ---------------------------------------------------------------------------
// Kernel 2: per-pair MLP.  lane = pair. 1 wave per block, no barriers.
// acc[152] registers carry layer-1; h1 goes through LDS [k][lane] (stride-64,
// 2-way conflict = free) so layer-2's k-loop stays dynamic (compact code).
// ---------------------------------------------------------------------------
__global__ __launch_bounds__(64, 1)
void pair_mlp(const float* __restrict__ g_i,
              const float* __restrict__ ms,
              const int* __restrict__ mention_ids,
              const int* __restrict__ antecedent_ids,
              const int* __restrict__ distances,
              const float* __restrict__ b3,
              const float* __restrict__ ws,
              float* __restrict__ out2, int P) {
  __shared__ float h1s[HID_P * 64];
  int lane = threadIdx.x;
  int p = blockIdx.x * 64 + lane;
  if (p >= P) return;

  int i = mention_ids[p];
  int j = antecedent_ids[p];
  int d = distances[p];
  int didx = (d >= 1) + (d >= 2) + (d >= 3) + (d >= 4) +
             (d >= 8) + (d >= 16) + (d >= 32) + (d >= 64);

  const float4* U  = (const float4*)(ws + OFF_U + (size_t)i    * HID_P);
  const float4* V  = (const float4*)(ws + OFF_V + (size_t)j    * HID_P);
  const float4* Dt = (const float4*)(ws + OFF_D + (size_t)didx * HID_P);

  float acc[HID_P];
#pragma unroll
  for (int c4 = 0; c4 < NB_H4; c4++) {
    float4 u = U[c4], v = V[c4], dd = Dt[c4];
    acc[4 * c4 + 0] = u.x + v.x + dd.x;
    acc[4 * c4 + 1] = u.y + v.y + dd.y;
    acc[4 * c4 + 2] = u.z + v.z + dd.z;
    acc[4 * c4 + 3] = u.w + v.w + dd.w;
  }

  // bilinear term: acc[h] += sum_k i_g[k]*j_g[k]*Wc[k][h]
  const float4* irow = (const float4*)(g_i + (size_t)i * GDIM);
  const float4* jrow = (const float4*)(g_i + (size_t)j * GDIM);
  const float* Wc = ws + OFF_WC;

  float4 a4 = irow[0], x4 = jrow[0];
  for (int k4 = 0; k4 < GDIM / 4; k4++) {
    float4 a = a4, x = x4;
    int nk = (k4 + 1 < GDIM / 4) ? k4 + 1 : k4;   // prefetch next i/j chunk
    a4 = irow[nk];
    x4 = jrow[nk];
    float xsv[4] = { a.x * x.x, a.y * x.y, a.z * x.z, a.w * x.w };
    const float* wbase = Wc + (size_t)(4 * k4) * HID_P;
#pragma unroll
    for (int kk = 0; kk < 4; kk++) {
      float xs = xsv[kk];
      const float4* w4 = (const float4*)(wbase + (size_t)kk * HID_P);
#pragma unroll
      for (int c4 = 0; c4 < NB_H4; c4++) {
        float4 w = w4[c4];
        acc[4 * c4 + 0] = fmaf(xs, w.x, acc[4 * c4 + 0]);
        acc[4 * c4 + 1] = fmaf(xs, w.y, acc[4 * c4 + 1]);
        acc[4 * c4 + 2] = fmaf(xs, w.z, acc[4 * c4 + 2]);
        acc[4 * c4 + 3] = fmaf(xs, w.w, acc[4 * c4 + 3]);
      }
    }
  }

  // relu -> LDS (per-lane private spill; no cross-lane use, no barrier needed)
#pragma unroll
  for (int c = 0; c < HID_P; c++) h1s[c * 64 + lane] = fmaxf(acc[c], 0.f);

  // layer 2
  const float* W2p = ws + OFF_W2;
  const float4* b2p = (const float4*)(ws + OFF_B2);
  float acc2[HID_P];
#pragma unroll
  for (int c4 = 0; c4 < NB_H4; c4++) {
    float4 b = b2p[c4];
    acc2[4 * c4 + 0] = b.x; acc2[4 * c4 + 1] = b.y;
    acc2[4 * c4 + 2] = b.z; acc2[4 * c4 + 3] = b.w;
  }
  float xk = h1s[lane];
  for (int k = 0; k < HID_P; k++) {
    float x = xk;
    int kn = (k + 1 < HID_P) ? k + 1 : k;
    xk = h1s[kn * 64 + lane];                     // prefetch next h1 value
    const float4* w4 = (const float4*)(W2p + (size_t)k * HID_P);
#pragma unroll
    for (int c4 = 0; c4 < NB_H4; c4++) {
      float4 w = w4[c4];
      acc2[4 * c4 + 0] = fmaf(x, w.x, acc2[4 * c4 + 0]);
      acc2[4 * c4 + 1] = fmaf(x, w.y, acc2[4 * c4 + 1]);
      acc2[4 * c4 + 2] = fmaf(x, w.z, acc2[4 * c4 + 2]);
      acc2[4 * c4 + 3] = fmaf(x, w.w, acc2[4 * c4 + 3]);
    }
  }

  // layer 3 (relu fused) + mention scores
  const float4* W3p = (const float4*)(ws + OFF_W3);
  float s = b3[0];
#pragma unroll
  for (int c4 = 0; c4 < NB_H4; c4++) {
    float4 w = W3p[c4];
    s = fmaf(fmaxf(acc2[4 * c4 + 0], 0.f), w.x, s);
    s = fmaf(fmaxf(acc2[4 * c4 + 1], 0.f), w.y, s);
    s = fmaf(fmaxf(acc2[4 * c4 + 2], 0.f), w.z, s);
    s = fmaf(fmaxf(acc2[4 * c4 + 3], 0.f), w.w, s);
  }
  float cval = ms[i] + ms[j] + s;
  ((float2*)out2)[p] = make_float2(0.f, cval);
}

// ---------------------------------------------------------------------------
// Kernel 3: per-group softmax rows (wave per row)
// ---------------------------------------------------------------------------
__global__ __launch_bounds__(64, 1)
void softmax_rows(const float* __restrict__ out2,
                  float* __restrict__ probs, int G) {
  int b = blockIdx.x;
  int t = threadIdx.x;
  if (b == 0) {                       // special first row
    for (int pos = t; pos <= KMAX; pos += 64)
      probs[pos] = (pos == 0) ? 1.0f : 1000.0f;
    return;
  }
  int g = b - 1;                      // segment id; lengths[g] = min(g+1, KMAX)
  int L = (g + 1 < KMAX) ? g + 1 : KMAX;
  int base = (g <= KMAX) ? g * (g + 1) / 2
                         : KMAX * (KMAX + 1) / 2 + (g - KMAX) * KMAX;
  float mx = 0.f;                     // includes the implicit 0.0 at pos L
  for (int pos = t; pos < L; pos += 64)
    mx = fmaxf(mx, out2[2 * (base + pos) + 1]);
#pragma unroll
  for (int off = 32; off >= 1; off >>= 1) mx = fmaxf(mx, __shfl_xor(mx, off));

  float sum = (t == 0) ? expf(-mx) : 0.f;   // the 0.0 entry at pos L
  for (int pos = t; pos < L; pos += 64)
    sum += expf(out2[2 * (base + pos) + 1] - mx);
#pragma unroll
  for (int off = 32; off >= 1; off >>= 1) sum += __shfl_xor(sum, off);
  float inv = 1.f / sum;

  float* row = probs + (size_t)(g + 1) * (KMAX + 1);
  for (int pos = t; pos <= KMAX; pos += 64) {
    float v;
    if (pos < L)       v = expf(out2[2 * (base + pos) + 1] - mx) * inv;
    else if (pos == L) v = expf(-mx) * inv;
    else               v = 1000.0f;
    row[pos] = v;
  }
}

// ---------------------------------------------------------------------------
extern "C" void kernel_launch(void* const* d_in, const int* in_sizes, int n_in,
                              void* d_out, int out_size, void* d_ws, size_t ws_size,
                              hipStream_t stream) {
  const float* g_i        = (const float*)d_in[0];
  const float* ms         = (const float*)d_in[1];
  const float* dist_embed = (const float*)d_in[2];
  const float* W1         = (const float*)d_in[3];
  const float* b1         = (const float*)d_in[4];
  const float* W2         = (const float*)d_in[5];
  const float* b2         = (const float*)d_in[6];
  const float* W3         = (const float*)d_in[7];
  const float* b3         = (const float*)d_in[8];
  const int* mid          = (const int*)d_in[9];
  const int* aid          = (const int*)d_in[10];
  const int* dist         = (const int*)d_in[11];

  int N = in_sizes[0] / GDIM;     // 2000
  int P = in_sizes[9];            // 468625
  int G = in_sizes[14];           // 1999

  float* ws    = (float*)d_ws;
  float* probs = (float*)d_out;
  float* out2  = (float*)d_out + (size_t)(G + 1) * (KMAX + 1);

  int tot_uv = 2 * N * HID_P;
  precompute_uv<<<(tot_uv + 255) / 256, 256, 0, stream>>>(g_i, W1, b1, ws, N);
  int tot_tab = 9 * HID_P + GDIM * HID_P + HID_P * HID_P + 2 * HID_P;
  precompute_tabs<<<(tot_tab + 255) / 256, 256, 0, stream>>>(dist_embed, W1, W2, b2, W3, ws);
  pair_mlp<<<(P + 63) / 64, 64, 0, stream>>>(g_i, ms, mid, aid, dist, b3, ws, out2, P);
  softmax_rows<<<G + 1, 64, 0, stream>>>(out2, probs, G);
}